// Round 2
// baseline (811.305 us; speedup 1.0000x reference)
//
#include <hip/hip_runtime.h>
#include <stdint.h>

typedef unsigned short ushort_t;
typedef __attribute__((ext_vector_type(8))) __bf16 bf16x8;
typedef __attribute__((ext_vector_type(4))) float f32x4;

#define GPTR(x) ((__attribute__((address_space(1))) void*)(x))
#define LPTR(x) ((__attribute__((address_space(3))) void*)(x))

__device__ __forceinline__ ushort_t f2b(float f) {
  union { float f; uint32_t i; } v; v.f = f;
  uint32_t x = v.i;
  uint32_t r = (x + 0x7FFFu + ((x >> 16) & 1u)) >> 16;  // RNE; fine for finite data
  return (ushort_t)r;
}

__device__ __forceinline__ void spline_expand(float x, float* sil, float* b /*8*/) {
  *sil = x / (1.0f + __expf(-x));
  float g[12];
#pragma unroll
  for (int j = 0; j < 12; ++j) g[j] = (float)(j - 3) * 0.4f - 1.0f;
  float t[11];
#pragma unroll
  for (int j = 0; j < 11; ++j) t[j] = (x >= g[j] && x < g[j + 1]) ? 1.0f : 0.0f;
#pragma unroll
  for (int k = 1; k <= 3; ++k) {
#pragma unroll
    for (int j = 0; j + k < 11; ++j) {
      float i1 = 1.0f / (g[j + k] - g[j]);        // constant-folded after unroll
      float i2 = 1.0f / (g[j + k + 1] - g[j + 1]);
      t[j] = (x - g[j]) * i1 * t[j] + (g[j + k + 1] - x) * i2 * t[j + 1];
    }
  }
#pragma unroll
  for (int k = 0; k < 8; ++k) b[k] = t[k];
}

// fp32 x -> bf16 augmented A row chunk [silu, B0..B7] per feature; pad cols zeroed.
__global__ void expand_kernel(const float* __restrict__ xin, ushort_t* __restrict__ A,
                              int rows, int in_f, int ldA) {
  int idx = blockIdx.x * 256 + threadIdx.x;
  int total = rows * in_f;
  if (idx >= total) return;
  int r = idx / in_f;
  int i = idx - r * in_f;
  float x = xin[idx];
  float sil, b[8];
  spline_expand(x, &sil, b);
  ushort_t* o = A + (size_t)r * ldA + (size_t)i * 9;
  o[0] = f2b(sil);
#pragma unroll
  for (int k = 0; k < 8; ++k) o[1 + k] = f2b(b[k]);
  if (i == in_f - 1) {
    for (int t = in_f * 9; t < ldA; ++t) A[(size_t)r * ldA + t] = 0;
  }
}

// fp32 weights -> bf16 augmented W: W[o,9i]=bw[o,i]; W[o,9i+1+k]=sw[o,i,k]*sc[o,i].
__global__ void prepw_kernel(const float* __restrict__ bw, const float* __restrict__ sw,
                             const float* __restrict__ sc, ushort_t* __restrict__ W,
                             int out_f, int out_p, int in_f, int ldW) {
  int idx = blockIdx.x * 256 + threadIdx.x;
  int total = out_p * in_f;
  if (idx >= total) return;
  int o = idx / in_f;
  int i = idx - o * in_f;
  ushort_t* w = W + (size_t)o * ldW + (size_t)i * 9;
  if (o < out_f) {
    size_t base = (size_t)o * in_f + i;
    float s = sc[base];
    w[0] = f2b(bw[base]);
#pragma unroll
    for (int k = 0; k < 8; ++k) w[1 + k] = f2b(sw[base * 8 + k] * s);
  } else {
#pragma unroll
    for (int k = 0; k < 9; ++k) w[k] = 0;
  }
  if (i == in_f - 1) {
    for (int t = in_f * 9; t < ldW; ++t) W[(size_t)o * ldW + t] = 0;
  }
}

// m97-style bf16 GEMM, A [M,K] rm, Bw=B^T [N,K] rm, K-split partials P[s,m,n] fp32.
// 128x128 tile, BK=32, 4 waves of 4x4 16x16x32 MFMA.
__global__ __launch_bounds__(256) void gemm_kernel(
    const ushort_t* __restrict__ A, const ushort_t* __restrict__ Bw,
    float* __restrict__ P, int M, int N, int K, int kpb) {
  __shared__ __align__(16) ushort_t As[128 * 32];
  __shared__ __align__(16) ushort_t Bs[128 * 32];
  const int tid = threadIdx.x;
  const int m0 = blockIdx.x * 128;
  const int n0 = blockIdx.y * 128;
  const int s = blockIdx.z;
  const int nK = K >> 5;
  int k0 = s * kpb;
  int k1 = k0 + kpb; if (k1 > nK) k1 = nK;
  const int lane = tid & 63;
  const int wv = tid >> 6;
  const int wm = wv & 1, wn = wv >> 1;
  const int l15 = lane & 15, lq = lane >> 4;

  f32x4 acc[4][4];
#pragma unroll
  for (int a = 0; a < 4; ++a)
#pragma unroll
    for (int b = 0; b < 4; ++b) acc[a][b] = {0.0f, 0.0f, 0.0f, 0.0f};

  // u = it*256+tid; LDS offset u*16B == wave-uniform base + lane*16 (global_load_lds constraint)
  const int u0 = tid, u1 = tid + 256;
  const int rA0 = u0 >> 2, sA0 = u0 & 3;
  const int rA1 = u1 >> 2, sA1 = u1 & 3;
  const ushort_t* gA0 = A + (size_t)(m0 + rA0) * K + sA0 * 8;
  const ushort_t* gA1 = A + (size_t)(m0 + rA1) * K + sA1 * 8;
  const ushort_t* gB0 = Bw + (size_t)(n0 + rA0) * K + sA0 * 8;
  const ushort_t* gB1 = Bw + (size_t)(n0 + rA1) * K + sA1 * 8;
  ushort_t* lA0 = &As[u0 * 8];
  ushort_t* lA1 = &As[u1 * 8];
  ushort_t* lB0 = &Bs[u0 * 8];
  ushort_t* lB1 = &Bs[u1 * 8];

  for (int kk = k0; kk < k1; ++kk) {
    const int kb = kk << 5;
    __syncthreads();
    __builtin_amdgcn_global_load_lds(GPTR(gA0 + kb), LPTR(lA0), 16, 0, 0);
    __builtin_amdgcn_global_load_lds(GPTR(gA1 + kb), LPTR(lA1), 16, 0, 0);
    __builtin_amdgcn_global_load_lds(GPTR(gB0 + kb), LPTR(lB0), 16, 0, 0);
    __builtin_amdgcn_global_load_lds(GPTR(gB1 + kb), LPTR(lB1), 16, 0, 0);
    __syncthreads();
    bf16x8 aF[4], bF[4];
#pragma unroll
    for (int t = 0; t < 4; ++t) {
      aF[t] = *(const bf16x8*)(&As[(wm * 64 + t * 16 + l15) * 32 + lq * 8]);
      bF[t] = *(const bf16x8*)(&Bs[(wn * 64 + t * 16 + l15) * 32 + lq * 8]);
    }
#pragma unroll
    for (int ti = 0; ti < 4; ++ti)
#pragma unroll
      for (int tj = 0; tj < 4; ++tj)
        acc[ti][tj] = __builtin_amdgcn_mfma_f32_16x16x32_bf16(aF[ti], bF[tj], acc[ti][tj], 0, 0, 0);
  }

  float* Pp = P + (size_t)s * M * N;
#pragma unroll
  for (int ti = 0; ti < 4; ++ti) {
#pragma unroll
    for (int tj = 0; tj < 4; ++tj) {
      int gr = m0 + wm * 64 + ti * 16 + lq * 4;
      int gc = n0 + wn * 64 + tj * 16 + l15;
#pragma unroll
      for (int rr = 0; rr < 4; ++rr) {
        Pp[(size_t)(gr + rr) * N + gc] = acc[ti][tj][rr];
      }
    }
  }
}

// Sum S layer-1 partials -> relu -> spline-expand directly into A2 (bf16). N must be 512.
__global__ void reduce_expand_kernel(const float* __restrict__ P, ushort_t* __restrict__ A2,
                                     int M, int S) {
  int idx = blockIdx.x * 256 + threadIdx.x;
  int total = M * 512;
  if (idx >= total) return;
  float v = 0.0f;
  for (int s = 0; s < S; ++s) v += P[(size_t)s * total + idx];
  if (v < 0.0f) v = 0.0f;
  int r = idx >> 9, i = idx & 511;
  float sil, b[8];
  spline_expand(v, &sil, b);
  ushort_t* o = A2 + (size_t)r * 4608 + (size_t)i * 9;
  o[0] = f2b(sil);
#pragma unroll
  for (int k = 0; k < 8; ++k) o[1 + k] = f2b(b[k]);
}

// Sum S layer-2 partials, drop pad cols, write fp32 out (row stride Nout).
__global__ void reduce_out_kernel(const float* __restrict__ P, float* __restrict__ out,
                                  int M, int N, int S, int Nout) {
  int idx = blockIdx.x * 256 + threadIdx.x;
  int total = M * N;
  if (idx >= total) return;
  float v = 0.0f;
  for (int s = 0; s < S; ++s) v += P[(size_t)s * total + idx];
  int r = idx / N, c = idx - r * N;
  if (c < Nout) out[(size_t)r * Nout + c] = v;
}

static inline size_t alup(size_t x) { return (x + 255) & ~(size_t)255; }

extern "C" void kernel_launch(void* const* d_in, const int* in_sizes, int n_in,
                              void* d_out, int out_size, void* d_ws, size_t ws_size,
                              hipStream_t stream) {
  const float* fp  = (const float*)d_in[0];   // [8192, 2513] fp32
  const float* bw1 = (const float*)d_in[1];   // [512, 2513]
  const float* sw1 = (const float*)d_in[2];   // [512, 2513, 8]
  const float* sc1 = (const float*)d_in[3];   // [512, 2513]
  const float* bw2 = (const float*)d_in[4];   // [300, 512]
  const float* sw2 = (const float*)d_in[5];   // [300, 512, 8]
  const float* sc2 = (const float*)d_in[6];   // [300, 512]
  float* out = (float*)d_out;                 // [8192, 300] fp32

  const int Btot = 8192, IN1 = 2513, O1 = 512, K1 = 22624;
  const int IN2 = 512, O2 = 300, O2P = 384, K2 = 4608;
  const size_t szW1 = (size_t)O1 * K1 * 2;
  const size_t szW2 = (size_t)O2P * K2 * 2;

  // Adaptive chunking: largest CH that fits ws_size; K-split keeps gemm grids ~768 blocks.
  int CH = 256, S1 = 1, S2 = 1;
  {
    const int chs[8]  = {8192, 4096, 2048, 1024, 512, 256, 256, 256};
    const int s1s[8]  = {3, 6, 12, 24, 48, 96, 4, 1};
    const int s2s[8]  = {4, 8, 16, 32, 64, 128, 4, 1};
    for (int t = 0; t < 8; ++t) {
      int ch = chs[t], s1 = s1s[t], s2 = s2s[t];
      size_t p1 = (size_t)s1 * ch * O1 * 4, p2 = (size_t)s2 * ch * O2P * 4;
      size_t szP = p1 > p2 ? p1 : p2;
      size_t need = alup(szW1) + alup(szW2) + alup(szP)
                  + alup((size_t)ch * K2 * 2) + alup((size_t)ch * K1 * 2);
      CH = ch; S1 = s1; S2 = s2;
      if (need <= ws_size) break;   // else degrade; last tier used regardless
    }
  }

  char* wp = (char*)d_ws;
  size_t off = 0;
  size_t p1 = (size_t)S1 * CH * O1 * 4, p2 = (size_t)S2 * CH * O2P * 4;
  size_t szP = p1 > p2 ? p1 : p2;
  ushort_t* W1a = (ushort_t*)(wp + off); off += alup(szW1);
  ushort_t* W2a = (ushort_t*)(wp + off); off += alup(szW2);
  float*    P   = (float*)(wp + off);    off += alup(szP);
  ushort_t* A2c = (ushort_t*)(wp + off); off += alup((size_t)CH * K2 * 2);
  ushort_t* A1c = (ushort_t*)(wp + off); off += alup((size_t)CH * K1 * 2);

  {
    int tot = O1 * IN1;
    prepw_kernel<<<(tot + 255) / 256, 256, 0, stream>>>(bw1, sw1, sc1, W1a, O1, O1, IN1, K1);
  }
  {
    int tot = O2P * IN2;
    prepw_kernel<<<(tot + 255) / 256, 256, 0, stream>>>(bw2, sw2, sc2, W2a, O2, O2P, IN2, K2);
  }

  const int nK1 = K1 >> 5, nK2 = K2 >> 5;
  const int kpb1 = (nK1 + S1 - 1) / S1;
  const int kpb2 = (nK2 + S2 - 1) / S2;
  const int nch = Btot / CH;
  for (int c = 0; c < nch; ++c) {
    const float* xc = fp + (size_t)c * CH * IN1;
    int tot1 = CH * IN1;
    expand_kernel<<<(tot1 + 255) / 256, 256, 0, stream>>>(xc, A1c, CH, IN1, K1);
    gemm_kernel<<<dim3(CH / 128, O1 / 128, S1), 256, 0, stream>>>(A1c, W1a, P, CH, O1, K1, kpb1);
    int tot2 = CH * O1;
    reduce_expand_kernel<<<(tot2 + 255) / 256, 256, 0, stream>>>(P, A2c, CH, S1);
    gemm_kernel<<<dim3(CH / 128, O2P / 128, S2), 256, 0, stream>>>(A2c, W2a, P, CH, O2P, K2, kpb2);
    int tot3 = CH * O2P;
    reduce_out_kernel<<<(tot3 + 255) / 256, 256, 0, stream>>>(P, out + (size_t)c * CH * O2, CH, O2P, S2, O2);
  }
  (void)in_sizes; (void)n_in; (void)out_size;
}

// Round 3
// 788.236 us; speedup vs baseline: 1.0293x; 1.0293x over previous
//
#include <hip/hip_runtime.h>
#include <stdint.h>

typedef unsigned short ushort_t;
typedef __attribute__((ext_vector_type(8))) __bf16 bf16x8;
typedef __attribute__((ext_vector_type(4))) float f32x4;
typedef __attribute__((ext_vector_type(4))) uint32_t u32x4;
typedef __attribute__((ext_vector_type(4))) float float4_t;

#define GPTR(x) ((__attribute__((address_space(1))) void*)(x))
#define LPTR(x) ((__attribute__((address_space(3))) void*)(x))

__device__ __forceinline__ ushort_t f2b(float f) {
  union { float f; uint32_t i; } v; v.f = f;
  uint32_t x = v.i;
  uint32_t r = (x + 0x7FFFu + ((x >> 16) & 1u)) >> 16;  // RNE; finite data only
  return (ushort_t)r;
}

__device__ __forceinline__ void spline_expand(float x, float* sil, float* b /*8*/) {
  *sil = x / (1.0f + __expf(-x));
  float g[12];
#pragma unroll
  for (int j = 0; j < 12; ++j) g[j] = (float)(j - 3) * 0.4f - 1.0f;
  float t[11];
#pragma unroll
  for (int j = 0; j < 11; ++j) t[j] = (x >= g[j] && x < g[j + 1]) ? 1.0f : 0.0f;
#pragma unroll
  for (int k = 1; k <= 3; ++k) {
#pragma unroll
    for (int j = 0; j + k < 11; ++j) {
      float i1 = 1.0f / (g[j + k] - g[j]);        // constant-folded after unroll
      float i2 = 1.0f / (g[j + k + 1] - g[j + 1]);
      t[j] = (x - g[j]) * i1 * t[j] + (g[j + k + 1] - x) * i2 * t[j + 1];
    }
  }
#pragma unroll
  for (int k = 0; k < 8; ++k) b[k] = t[k];
}

#define FPC 1024  // features per chunk; LDS = FPC*9 ushorts = 18432 B

// x[row, in_f] fp32 -> A[row, LDE] bf16 augmented [silu,B0..7]*in_f + zero pad.
// grid: (rows, ceil(LDE/(FPC*9))). LDS-staged, coalesced 16B stores.
__global__ __launch_bounds__(256) void expand_stage(
    const float* __restrict__ xin, ushort_t* __restrict__ A, int in_f, int LDE) {
  __shared__ __align__(16) ushort_t sb[FPC * 9];
  const int row = blockIdx.x, chunk = blockIdx.y, tid = threadIdx.x;
  const int e0 = chunk * (FPC * 9);
  int e1 = e0 + FPC * 9; if (e1 > LDE) e1 = LDE;
  const int ce = e1 - e0;                 // elements in this chunk (even by construction)
  for (int t = tid; t < (ce >> 1); t += 256) ((uint32_t*)sb)[t] = 0;
  __syncthreads();
  const int f0 = chunk * FPC;
  const float* xr = xin + (size_t)row * in_f;
#pragma unroll
  for (int j = 0; j < FPC; j += 256) {
    int f = f0 + j + tid;
    if (f < in_f) {
      float sil, b[8];
      spline_expand(xr[f], &sil, b);
      ushort_t* o = &sb[(j + tid) * 9];
      o[0] = f2b(sil);
#pragma unroll
      for (int k = 0; k < 8; ++k) o[1 + k] = f2b(b[k]);
    }
  }
  __syncthreads();
  u32x4* dst = (u32x4*)(A + (size_t)row * LDE + e0);
  const u32x4* src = (const u32x4*)sb;
  const int n16 = ce >> 3;                // 16B chunks
  for (int t = tid; t < n16; t += 256) dst[t] = src[t];
}

// Augmented weights, LDS-staged: W[o,9i]=bw[o,i]; W[o,9i+1+k]=sw[o,i,k]*sc[o,i].
// grid: (out_p, ceil(LDE/(FPC*9))). Pad rows (o>=out_f) and pad cols zeroed.
__global__ __launch_bounds__(256) void prepw_stage(
    const float* __restrict__ bw, const float* __restrict__ sw,
    const float* __restrict__ sc, ushort_t* __restrict__ W,
    int out_f, int in_f, int LDE) {
  __shared__ __align__(16) ushort_t sb[FPC * 9];
  const int o = blockIdx.x, chunk = blockIdx.y, tid = threadIdx.x;
  const int e0 = chunk * (FPC * 9);
  int e1 = e0 + FPC * 9; if (e1 > LDE) e1 = LDE;
  const int ce = e1 - e0;
  for (int t = tid; t < (ce >> 1); t += 256) ((uint32_t*)sb)[t] = 0;
  __syncthreads();
  const int f0 = chunk * FPC;
  if (o < out_f) {
#pragma unroll
    for (int j = 0; j < FPC; j += 256) {
      int f = f0 + j + tid;
      if (f < in_f) {
        size_t base = (size_t)o * in_f + f;
        float s = sc[base];
        float4_t s0 = ((const float4_t*)(sw + base * 8))[0];
        float4_t s1 = ((const float4_t*)(sw + base * 8))[1];
        ushort_t* w = &sb[(j + tid) * 9];
        w[0] = f2b(bw[base]);
        w[1] = f2b(s0.x * s); w[2] = f2b(s0.y * s);
        w[3] = f2b(s0.z * s); w[4] = f2b(s0.w * s);
        w[5] = f2b(s1.x * s); w[6] = f2b(s1.y * s);
        w[7] = f2b(s1.z * s); w[8] = f2b(s1.w * s);
      }
    }
  }
  __syncthreads();
  u32x4* dst = (u32x4*)(W + (size_t)o * LDE + e0);
  const u32x4* src = (const u32x4*)sb;
  const int n16 = ce >> 3;
  for (int t = tid; t < n16; t += 256) dst[t] = src[t];
}

// Sum S layer-1 partials -> relu -> expand into A2 row (512 feats -> 4608 elems).
// grid: (M). LDS-staged, coalesced stores.
__global__ __launch_bounds__(256) void reduce_expand_stage(
    const float* __restrict__ P, ushort_t* __restrict__ A2, int M, int S) {
  __shared__ __align__(16) ushort_t sb[4608];
  const int row = blockIdx.x, tid = threadIdx.x;
  const size_t total = (size_t)M * 512;
#pragma unroll
  for (int j = 0; j < 512; j += 256) {
    int f = j + tid;
    float v = 0.0f;
    for (int s = 0; s < S; ++s) v += P[(size_t)s * total + (size_t)row * 512 + f];
    if (v < 0.0f) v = 0.0f;
    float sil, b[8];
    spline_expand(v, &sil, b);
    ushort_t* o = &sb[f * 9];
    o[0] = f2b(sil);
#pragma unroll
    for (int k = 0; k < 8; ++k) o[1 + k] = f2b(b[k]);
  }
  __syncthreads();
  u32x4* dst = (u32x4*)(A2 + (size_t)row * 4608);
  const u32x4* src = (const u32x4*)sb;
  for (int t = tid; t < 576; t += 256) dst[t] = src[t];
}

// m97-style bf16 GEMM, A [M,K] rm, Bw=B^T [N,K] rm, K-split partials P[s,m,n] fp32.
__global__ __launch_bounds__(256) void gemm_kernel(
    const ushort_t* __restrict__ A, const ushort_t* __restrict__ Bw,
    float* __restrict__ P, int M, int N, int K, int kpb) {
  __shared__ __align__(16) ushort_t As[128 * 32];
  __shared__ __align__(16) ushort_t Bs[128 * 32];
  const int tid = threadIdx.x;
  const int m0 = blockIdx.x * 128;
  const int n0 = blockIdx.y * 128;
  const int s = blockIdx.z;
  const int nK = K >> 5;
  int k0 = s * kpb;
  int k1 = k0 + kpb; if (k1 > nK) k1 = nK;
  const int lane = tid & 63;
  const int wv = tid >> 6;
  const int wm = wv & 1, wn = wv >> 1;
  const int l15 = lane & 15, lq = lane >> 4;

  f32x4 acc[4][4];
#pragma unroll
  for (int a = 0; a < 4; ++a)
#pragma unroll
    for (int b = 0; b < 4; ++b) acc[a][b] = {0.0f, 0.0f, 0.0f, 0.0f};

  const int u0 = tid, u1 = tid + 256;
  const int rA0 = u0 >> 2, sA0 = u0 & 3;
  const int rA1 = u1 >> 2, sA1 = u1 & 3;
  const ushort_t* gA0 = A + (size_t)(m0 + rA0) * K + sA0 * 8;
  const ushort_t* gA1 = A + (size_t)(m0 + rA1) * K + sA1 * 8;
  const ushort_t* gB0 = Bw + (size_t)(n0 + rA0) * K + sA0 * 8;
  const ushort_t* gB1 = Bw + (size_t)(n0 + rA1) * K + sA1 * 8;
  ushort_t* lA0 = &As[u0 * 8];
  ushort_t* lA1 = &As[u1 * 8];
  ushort_t* lB0 = &Bs[u0 * 8];
  ushort_t* lB1 = &Bs[u1 * 8];

  for (int kk = k0; kk < k1; ++kk) {
    const int kb = kk << 5;
    __syncthreads();
    __builtin_amdgcn_global_load_lds(GPTR(gA0 + kb), LPTR(lA0), 16, 0, 0);
    __builtin_amdgcn_global_load_lds(GPTR(gA1 + kb), LPTR(lA1), 16, 0, 0);
    __builtin_amdgcn_global_load_lds(GPTR(gB0 + kb), LPTR(lB0), 16, 0, 0);
    __builtin_amdgcn_global_load_lds(GPTR(gB1 + kb), LPTR(lB1), 16, 0, 0);
    __syncthreads();
    bf16x8 aF[4], bF[4];
#pragma unroll
    for (int t = 0; t < 4; ++t) {
      aF[t] = *(const bf16x8*)(&As[(wm * 64 + t * 16 + l15) * 32 + lq * 8]);
      bF[t] = *(const bf16x8*)(&Bs[(wn * 64 + t * 16 + l15) * 32 + lq * 8]);
    }
#pragma unroll
    for (int ti = 0; ti < 4; ++ti)
#pragma unroll
      for (int tj = 0; tj < 4; ++tj)
        acc[ti][tj] = __builtin_amdgcn_mfma_f32_16x16x32_bf16(aF[ti], bF[tj], acc[ti][tj], 0, 0, 0);
  }

  float* Pp = P + (size_t)s * M * N;
#pragma unroll
  for (int ti = 0; ti < 4; ++ti) {
#pragma unroll
    for (int tj = 0; tj < 4; ++tj) {
      int gr = m0 + wm * 64 + ti * 16 + lq * 4;
      int gc = n0 + wn * 64 + tj * 16 + l15;
#pragma unroll
      for (int rr = 0; rr < 4; ++rr) {
        Pp[(size_t)(gr + rr) * N + gc] = acc[ti][tj][rr];
      }
    }
  }
}

// Sum S layer-2 partials, drop pad cols, write fp32 out (row stride Nout).
__global__ void reduce_out_kernel(const float* __restrict__ P, float* __restrict__ out,
                                  int M, int N, int S, int Nout) {
  int idx = blockIdx.x * 256 + threadIdx.x;
  int total = M * N;
  if (idx >= total) return;
  float v = 0.0f;
  for (int s = 0; s < S; ++s) v += P[(size_t)s * total + idx];
  int r = idx / N, c = idx - r * N;
  if (c < Nout) out[(size_t)r * Nout + c] = v;
}

static inline size_t alup(size_t x) { return (x + 255) & ~(size_t)255; }

extern "C" void kernel_launch(void* const* d_in, const int* in_sizes, int n_in,
                              void* d_out, int out_size, void* d_ws, size_t ws_size,
                              hipStream_t stream) {
  const float* fp  = (const float*)d_in[0];   // [8192, 2513] fp32
  const float* bw1 = (const float*)d_in[1];   // [512, 2513]
  const float* sw1 = (const float*)d_in[2];   // [512, 2513, 8]
  const float* sc1 = (const float*)d_in[3];   // [512, 2513]
  const float* bw2 = (const float*)d_in[4];   // [300, 512]
  const float* sw2 = (const float*)d_in[5];   // [300, 512, 8]
  const float* sc2 = (const float*)d_in[6];   // [300, 512]
  float* out = (float*)d_out;                 // [8192, 300] fp32

  const int Btot = 8192, IN1 = 2513, O1 = 512, K1 = 22624;
  const int IN2 = 512, O2 = 300, O2P = 384, K2 = 4608;
  const size_t szW1 = (size_t)O1 * K1 * 2;
  const size_t szW2 = (size_t)O2P * K2 * 2;

  // Adaptive chunking: largest CH that fits ws_size; K-split keeps gemm grids ~768 blocks.
  int CH = 256, S1 = 1, S2 = 1;
  {
    const int chs[8]  = {8192, 4096, 2048, 1024, 512, 256, 256, 256};
    const int s1s[8]  = {3, 6, 12, 24, 48, 96, 4, 1};
    const int s2s[8]  = {4, 8, 16, 32, 64, 128, 4, 1};
    for (int t = 0; t < 8; ++t) {
      int ch = chs[t], s1 = s1s[t], s2 = s2s[t];
      size_t p1 = (size_t)s1 * ch * O1 * 4, p2 = (size_t)s2 * ch * O2P * 4;
      size_t szP = p1 > p2 ? p1 : p2;
      size_t need = alup(szW1) + alup(szW2) + alup(szP)
                  + alup((size_t)ch * K2 * 2) + alup((size_t)ch * K1 * 2);
      CH = ch; S1 = s1; S2 = s2;
      if (need <= ws_size) break;   // else degrade; last tier used regardless
    }
  }

  char* wp = (char*)d_ws;
  size_t off = 0;
  size_t p1 = (size_t)S1 * CH * O1 * 4, p2 = (size_t)S2 * CH * O2P * 4;
  size_t szP = p1 > p2 ? p1 : p2;
  ushort_t* W1a = (ushort_t*)(wp + off); off += alup(szW1);
  ushort_t* W2a = (ushort_t*)(wp + off); off += alup(szW2);
  float*    P   = (float*)(wp + off);    off += alup(szP);
  ushort_t* A2c = (ushort_t*)(wp + off); off += alup((size_t)CH * K2 * 2);
  ushort_t* A1c = (ushort_t*)(wp + off); off += alup((size_t)CH * K1 * 2);

  const int CH1 = (K1 + FPC * 9 - 1) / (FPC * 9);  // 3 chunks per 22624-elem row
  const int CH2 = (K2 + FPC * 9 - 1) / (FPC * 9);  // 1 chunk per 4608-elem row
  prepw_stage<<<dim3(O1, CH1), 256, 0, stream>>>(bw1, sw1, sc1, W1a, O1, IN1, K1);
  prepw_stage<<<dim3(O2P, CH2), 256, 0, stream>>>(bw2, sw2, sc2, W2a, O2, IN2, K2);

  const int nK1 = K1 >> 5, nK2 = K2 >> 5;
  const int kpb1 = (nK1 + S1 - 1) / S1;
  const int kpb2 = (nK2 + S2 - 1) / S2;
  const int nch = Btot / CH;
  for (int c = 0; c < nch; ++c) {
    const float* xc = fp + (size_t)c * CH * IN1;
    expand_stage<<<dim3(CH, CH1), 256, 0, stream>>>(xc, A1c, IN1, K1);
    gemm_kernel<<<dim3(CH / 128, O1 / 128, S1), 256, 0, stream>>>(A1c, W1a, P, CH, O1, K1, kpb1);
    reduce_expand_stage<<<CH, 256, 0, stream>>>(P, A2c, CH, S1);
    gemm_kernel<<<dim3(CH / 128, O2P / 128, S2), 256, 0, stream>>>(A2c, W2a, P, CH, O2P, K2, kpb2);
    int tot3 = CH * O2P;
    reduce_out_kernel<<<(tot3 + 255) / 256, 256, 0, stream>>>(P, out + (size_t)c * CH * O2, CH, O2P, S2, O2);
  }
  (void)in_sizes; (void)n_in; (void)out_size;
}